// Round 1
// baseline (22120.935 us; speedup 1.0000x reference)
//
#include <hip/hip_runtime.h>
#include <cstddef>

#define NN   2048
#define BB   32
#define TT   24
#define CIN  2
#define HH   64
#define EMBD 16
#define HOR  12
#define C1   66            // CIN + HID
#define C2   128           // HID + HID
#define COLS1 (BB*C1)      // 2112
#define COLS2 (BB*C2)      // 4096
#define NB   (NN*BB)       // 65536

// ---------------- A = softmax(relu(E E^T), axis=1) ----------------
__global__ __launch_bounds__(256) void compute_A_kernel(const float* __restrict__ E,
                                                        float* __restrict__ A) {
    __shared__ float srow[NN];
    __shared__ float sred[256];
    int row = blockIdx.x;
    float er[EMBD];
#pragma unroll
    for (int k = 0; k < EMBD; ++k) er[k] = E[row*EMBD + k];
    float lmax = -1e30f;
    for (int j = threadIdx.x; j < NN; j += 256) {
        const float* ej = E + j*EMBD;
        float d = 0.f;
#pragma unroll
        for (int k = 0; k < EMBD; ++k) d = fmaf(er[k], ej[k], d);
        d = fmaxf(d, 0.f);
        srow[j] = d;
        lmax = fmaxf(lmax, d);
    }
    sred[threadIdx.x] = lmax;
    __syncthreads();
    for (int s = 128; s > 0; s >>= 1) {
        if (threadIdx.x < s) sred[threadIdx.x] = fmaxf(sred[threadIdx.x], sred[threadIdx.x+s]);
        __syncthreads();
    }
    float rmax = sred[0];
    __syncthreads();
    float lsum = 0.f;
    for (int j = threadIdx.x; j < NN; j += 256) {
        float e = expf(srow[j] - rmax);
        srow[j] = e;
        lsum += e;
    }
    sred[threadIdx.x] = lsum;
    __syncthreads();
    for (int s = 128; s > 0; s >>= 1) {
        if (threadIdx.x < s) sred[threadIdx.x] += sred[threadIdx.x+s];
        __syncthreads();
    }
    float rinv = 1.f / sred[0];
    for (int j = threadIdx.x; j < NN; j += 256)
        A[(size_t)row*NN + j] = srow[j] * rinv;
}

// ---------------- scatter x_t into comb1's x slots ----------------
__global__ void scatter_x_kernel(const float* __restrict__ x, float* __restrict__ comb1, int t) {
    int idx = blockIdx.x*256 + threadIdx.x;
    if (idx >= BB*NN*CIN) return;
    int c  = idx & 1;
    int bn = idx >> 1;           // b*NN + n
    int n  = bn & (NN-1);
    int b  = bn >> 11;
    comb1[(size_t)(n*BB + b)*C1 + c] = x[(size_t)((b*TT + t)*NN + n)*CIN + c];
}

// ---------------- conv = A @ comb  (f32 tiled GEMM) ----------------
// A: [NN][NN], Bm: [NN][COLS], Cm: [NN][COLS]
template<int COLS>
__global__ __launch_bounds__(256) void gc_gemm(const float* __restrict__ A,
                                               const float* __restrict__ Bm,
                                               float* __restrict__ Cm) {
    __shared__ float As[16][68];   // transposed A tile: As[kk][row]
    __shared__ float Bs[16][68];   // Bs[kk][col]
    const int tx = threadIdx.x, ty = threadIdx.y;
    const int tid = ty*16 + tx;
    const int rowBase = blockIdx.y*64;
    const int colBase = blockIdx.x*64;
    const int ar = tid >> 2, ac4 = tid & 3;      // A loader: 64 rows x 4 float4
    const int br = tid >> 4, bc4 = tid & 15;     // B loader: 16 rows x 16 float4
    const float* aptr = A  + (size_t)(rowBase + ar)*NN + ac4*4;
    const float* bptr = Bm + (size_t)br*COLS + colBase + bc4*4;
    float acc[4][4] = {};
    for (int k0 = 0; k0 < NN; k0 += 16) {
        float4 a4 = *(const float4*)(aptr + k0);
        float4 b4 = *(const float4*)(bptr + (size_t)k0*COLS);
        As[ac4*4+0][ar] = a4.x;
        As[ac4*4+1][ar] = a4.y;
        As[ac4*4+2][ar] = a4.z;
        As[ac4*4+3][ar] = a4.w;
        *(float4*)&Bs[br][bc4*4] = b4;
        __syncthreads();
#pragma unroll
        for (int kk = 0; kk < 16; ++kk) {
            float4 av = *(const float4*)&As[kk][ty*4];
            float4 bv = *(const float4*)&Bs[kk][tx*4];
            float a[4] = {av.x, av.y, av.z, av.w};
            float b[4] = {bv.x, bv.y, bv.z, bv.w};
#pragma unroll
            for (int i = 0; i < 4; ++i)
#pragma unroll
                for (int j = 0; j < 4; ++j)
                    acc[i][j] = fmaf(a[i], b[j], acc[i][j]);
        }
        __syncthreads();
    }
#pragma unroll
    for (int i = 0; i < 4; ++i) {
        float4 o = make_float4(acc[i][0], acc[i][1], acc[i][2], acc[i][3]);
        *(float4*)(Cm + (size_t)(rowBase + ty*4 + i)*COLS + colBase + tx*4) = o;
    }
}

// ---------------- gates = conv @ W + b; LSTM cell update ----------------
// conv rows are (n*BB + b); each wave (64 lanes = hid unit k) handles 4 rows.
template<int C>
__global__ __launch_bounds__(256) void cell_update(const float* __restrict__ conv,
        const float* __restrict__ W, const float* __restrict__ bias,
        float* __restrict__ cbuf,
        float* __restrict__ h1out, int s1, int o1,
        float* __restrict__ h2out, int s2, int o2) {
    const int k = threadIdx.x & 63;
    const int w = threadIdx.x >> 6;
    const int rowBase = blockIdx.x*16 + w*4;
    float acc[4][4] = {};
    for (int c = 0; c < C; ++c) {
        float w0 = W[c*256 + k];
        float w1 = W[c*256 + 64 + k];
        float w2 = W[c*256 + 128 + k];
        float w3 = W[c*256 + 192 + k];
#pragma unroll
        for (int r = 0; r < 4; ++r) {
            float cv = conv[(size_t)(rowBase + r)*C + c];
            acc[r][0] = fmaf(cv, w0, acc[r][0]);
            acc[r][1] = fmaf(cv, w1, acc[r][1]);
            acc[r][2] = fmaf(cv, w2, acc[r][2]);
            acc[r][3] = fmaf(cv, w3, acc[r][3]);
        }
    }
    const float bi = bias[k], bf = bias[64+k], bg = bias[128+k], bo = bias[192+k];
#pragma unroll
    for (int r = 0; r < 4; ++r) {
        int row = rowBase + r;
        float gi = 1.f/(1.f + expf(-(acc[r][0] + bi)));
        float gf = 1.f/(1.f + expf(-(acc[r][1] + bf)));
        float gg = tanhf(acc[r][2] + bg);
        float go = 1.f/(1.f + expf(-(acc[r][3] + bo)));
        float cold = cbuf[(size_t)row*HH + k];
        float cnew = gf*cold + gi*gg;
        float h = go * tanhf(cnew);
        cbuf[(size_t)row*HH + k] = cnew;
        h1out[(size_t)row*s1 + o1 + k] = h;
        if (h2out) h2out[(size_t)row*s2 + o2 + k] = h;
    }
}

// ---------------- out = h2 @ Wp + bp, transposed to [B,HOR,N,1] ----------------
__global__ __launch_bounds__(256) void proj_kernel(const float* __restrict__ comb2,
        const float* __restrict__ Wp, const float* __restrict__ bp,
        float* __restrict__ out) {
    __shared__ float sW[HH*HOR];
    for (int i = threadIdx.x; i < HH*HOR; i += 256) sW[i] = Wp[i];
    __syncthreads();
    int idx = blockIdx.x*256 + threadIdx.x;   // b*NN + n
    if (idx >= BB*NN) return;
    int b = idx >> 11;
    int n = idx & (NN-1);
    const float* h = comb2 + (size_t)(n*BB + b)*C2 + HH;
    float acc[HOR];
#pragma unroll
    for (int j = 0; j < HOR; ++j) acc[j] = bp[j];
    for (int k = 0; k < HH; ++k) {
        float hv = h[k];
#pragma unroll
        for (int j = 0; j < HOR; ++j) acc[j] = fmaf(hv, sW[k*HOR + j], acc[j]);
    }
#pragma unroll
    for (int j = 0; j < HOR; ++j)
        out[(size_t)(b*HOR + j)*NN + n] = acc[j];
}

extern "C" void kernel_launch(void* const* d_in, const int* in_sizes, int n_in,
                              void* d_out, int out_size, void* d_ws, size_t ws_size,
                              hipStream_t stream) {
    const float* x  = (const float*)d_in[0];
    const float* E  = (const float*)d_in[1];
    const float* W1 = (const float*)d_in[2];
    const float* b1 = (const float*)d_in[3];
    const float* W2 = (const float*)d_in[4];
    const float* b2 = (const float*)d_in[5];
    const float* Wp = (const float*)d_in[6];
    const float* bp = (const float*)d_in[7];
    float* out = (float*)d_out;

    float* ws = (float*)d_ws;
    float* A     = ws;  ws += (size_t)NN*NN;      // 16.8 MB
    float* comb1 = ws;  ws += (size_t)NB*C1;      // [NB][66]
    float* comb2 = ws;  ws += (size_t)NB*C2;      // [NB][128]
    float* conv  = ws;  ws += (size_t)NB*C2;      // shared conv buffer (max layout)
    float* c1    = ws;  ws += (size_t)NB*HH;
    float* c2    = ws;  ws += (size_t)NB*HH;

    // deterministic state init every call (ws is NOT re-poisoned between replays)
    hipMemsetAsync(comb1, 0, sizeof(float)*(size_t)NB*C1, stream);
    hipMemsetAsync(comb2, 0, sizeof(float)*(size_t)NB*C2, stream);
    hipMemsetAsync(c1,    0, sizeof(float)*(size_t)NB*HH, stream);
    hipMemsetAsync(c2,    0, sizeof(float)*(size_t)NB*HH, stream);

    compute_A_kernel<<<NN, 256, 0, stream>>>(E, A);

    for (int t = 0; t < TT; ++t) {
        scatter_x_kernel<<<(BB*NN*CIN + 255)/256, 256, 0, stream>>>(x, comb1, t);
        // layer 1: conv = A @ [x_t, h1]
        gc_gemm<COLS1><<<dim3(COLS1/64, NN/64), dim3(16,16), 0, stream>>>(A, comb1, conv);
        // gates1 + cell: h1 -> comb1 (slot 2..65) and comb2 (slot 0..63)
        cell_update<C1><<<NB/16, 256, 0, stream>>>(conv, W1, b1, c1,
                                                   comb1, C1, CIN, comb2, C2, 0);
        // layer 2: conv = A @ [h1, h2]
        gc_gemm<COLS2><<<dim3(COLS2/64, NN/64), dim3(16,16), 0, stream>>>(A, comb2, conv);
        // gates2 + cell: h2 -> comb2 (slot 64..127)
        cell_update<C2><<<NB/16, 256, 0, stream>>>(conv, W2, b2, c2,
                                                   comb2, C2, HH, nullptr, 0, 0);
    }
    proj_kernel<<<(BB*NN + 255)/256, 256, 0, stream>>>(comb2, Wp, bp, out);
}

// Round 2
// 11164.935 us; speedup vs baseline: 1.9813x; 1.9813x over previous
//
#include <hip/hip_runtime.h>
#include <hip/hip_bf16.h>
#include <cstddef>
#include <cstdint>

#define NN   2048
#define BB   32
#define TT   24
#define CIN  2
#define HH   64
#define EMBD 16
#define HOR  12
#define C1   66            // CIN + HID
#define C2   128           // HID + HID
#define COLS1P 2176        // 34*64, padded col count for layer-1 GEMM
#define COLS2  4096
#define NB   (NN*BB)

using bfrag = __attribute__((ext_vector_type(8))) short;   // 8 bf16 = 4 VGPR
using f32x4 = __attribute__((ext_vector_type(4))) float;

static __device__ __forceinline__ short f2bf(float f) {
    __hip_bfloat16 h = __float2bfloat16(f);
    return *reinterpret_cast<short*>(&h);
}
static __device__ __forceinline__ float bf2f(short s) {
    __hip_bfloat16 h;
    *reinterpret_cast<short*>(&h) = s;
    return __bfloat162float(h);
}

#define AS1 __attribute__((address_space(1)))
#define AS3 __attribute__((address_space(3)))
static __device__ __forceinline__ void gload16(const short* g, short* l) {
    __builtin_amdgcn_global_load_lds((const AS1 void*)g, (AS3 void*)l, 16, 0, 0);
}

// ---------------- A = softmax(relu(E E^T)) -> split bf16 hi/lo ----------------
__global__ __launch_bounds__(256) void compute_A_kernel(const float* __restrict__ E,
                                                        short* __restrict__ Ahi,
                                                        short* __restrict__ Alo) {
    __shared__ float srow[NN];
    __shared__ float sred[256];
    int row = blockIdx.x;
    float er[EMBD];
#pragma unroll
    for (int k = 0; k < EMBD; ++k) er[k] = E[row*EMBD + k];
    float lmax = -1e30f;
    for (int j = threadIdx.x; j < NN; j += 256) {
        const float* ej = E + j*EMBD;
        float d = 0.f;
#pragma unroll
        for (int k = 0; k < EMBD; ++k) d = fmaf(er[k], ej[k], d);
        d = fmaxf(d, 0.f);
        srow[j] = d;
        lmax = fmaxf(lmax, d);
    }
    sred[threadIdx.x] = lmax;
    __syncthreads();
    for (int s = 128; s > 0; s >>= 1) {
        if (threadIdx.x < s) sred[threadIdx.x] = fmaxf(sred[threadIdx.x], sred[threadIdx.x+s]);
        __syncthreads();
    }
    float rmax = sred[0];
    __syncthreads();
    float lsum = 0.f;
    for (int j = threadIdx.x; j < NN; j += 256) {
        float e = expf(srow[j] - rmax);
        srow[j] = e;
        lsum += e;
    }
    sred[threadIdx.x] = lsum;
    __syncthreads();
    for (int s = 128; s > 0; s >>= 1) {
        if (threadIdx.x < s) sred[threadIdx.x] += sred[threadIdx.x+s];
        __syncthreads();
    }
    float rinv = 1.f / sred[0];
    for (int j = threadIdx.x; j < NN; j += 256) {
        float v = srow[j] * rinv;
        short h = f2bf(v);
        Ahi[(size_t)row*NN + j] = h;
        Alo[(size_t)row*NN + j] = f2bf(v - bf2f(h));
    }
}

// ---------------- scatter x_t -> comb1T rows (b*66+0/1), hi/lo ----------------
__global__ void scatter_xT_kernel(const float* __restrict__ x,
                                  short* __restrict__ hi, short* __restrict__ lo, int tstep) {
    int idx = blockIdx.x*256 + threadIdx.x;     // (b*2 + c)*2048 + n
    int n  = idx & (NN-1);
    int bc = idx >> 11;
    int c  = bc & 1, b = bc >> 1;
    float v = x[(size_t)((b*TT + tstep)*NN + n)*CIN + c];
    short h = f2bf(v);
    size_t row = (size_t)(b*C1 + c)*NN + n;
    hi[row] = h;
    lo[row] = f2bf(v - bf2f(h));
}

// ---------------- conv = A @ combT^T via 3-term split-bf16 MFMA ----------------
// Ahi/Alo: [2048 n][2048 m] bf16 row-major (K contiguous)
// Bhi/Blo: [cols][2048 m] bf16 row-major (K contiguous)  ("B^T input")
// Cout:    [2048 n][outStride] f32
template<int TN>   // tile cols: 128 or 64
__global__ __launch_bounds__(256) void gc_gemm_bf16(
        const short* __restrict__ Ahi, const short* __restrict__ Alo,
        const short* __restrict__ Bhi, const short* __restrict__ Blo,
        float* __restrict__ Cout, int outStride) {
    constexpr int NF = TN / 32;            // B frags per wave (2x2 wave grid)
    __shared__ short As[128*32];
    __shared__ short Bs[TN*32];
    const int t    = threadIdx.x;
    const int w    = t >> 6;
    const int lane = t & 63;
    const int wm = w >> 1, wn = w & 1;
    const int fr = lane & 15, fc = lane >> 4;
    const int rowbase = blockIdx.y * 128;
    const int colbase = blockIdx.x * TN;
    const int sr = t >> 2, sc = t & 3;     // staging: row, 16B chunk

    f32x4 acc[4][NF];
#pragma unroll
    for (int m = 0; m < 4; ++m)
#pragma unroll
        for (int n = 0; n < NF; ++n)
#pragma unroll
            for (int r = 0; r < 4; ++r) acc[m][n][r] = 0.f;

    short* aD0 = As + w*512;               // bytes w*1024
    short* aD1 = As + 2048 + w*512;
    short* bD0 = Bs + w*512;
    short* bD1 = Bs + 2048 + w*512;

    for (int p = 0; p < 3; ++p) {
        const short* Ag = (p == 2) ? Alo : Ahi;
        const short* Bg = (p == 1) ? Blo : Bhi;
        const short* aS0 = Ag + (size_t)(rowbase + sr)*NN + sc*8;
        const short* aS1 = Ag + (size_t)(rowbase + 64 + sr)*NN + sc*8;
        const short* bS0 = Bg + (size_t)(colbase + sr)*NN + sc*8;
        const short* bS1 = Bg + (size_t)(colbase + 64 + sr)*NN + sc*8;  // only TN==128
        for (int k0 = 0; k0 < NN; k0 += 32) {
            gload16(aS0 + k0, aD0);
            gload16(aS1 + k0, aD1);
            gload16(bS0 + k0, bD0);
            if constexpr (TN == 128) gload16(bS1 + k0, bD1);
            __syncthreads();
            bfrag af[4], bf[NF];
#pragma unroll
            for (int m = 0; m < 4; ++m)
                af[m] = *(const bfrag*)(As + (wm*64 + m*16 + fr)*32 + fc*8);
#pragma unroll
            for (int n = 0; n < NF; ++n)
                bf[n] = *(const bfrag*)(Bs + (wn*(TN/2) + n*16 + fr)*32 + fc*8);
#pragma unroll
            for (int m = 0; m < 4; ++m)
#pragma unroll
                for (int n = 0; n < NF; ++n)
                    acc[m][n] = __builtin_amdgcn_mfma_f32_16x16x32_bf16(af[m], bf[n], acc[m][n], 0, 0, 0);
            __syncthreads();
        }
    }
    // C/D layout: col = lane&15, row = (lane>>4)*4 + reg
#pragma unroll
    for (int m = 0; m < 4; ++m) {
        const int gr = rowbase + wm*64 + m*16 + fc*4;
#pragma unroll
        for (int n = 0; n < NF; ++n) {
            const int gc = colbase + wn*(TN/2) + n*16 + fr;
#pragma unroll
            for (int r = 0; r < 4; ++r)
                Cout[(size_t)(gr + r)*outStride + gc] = acc[m][n][r];
        }
    }
}

// ---------------- gates = conv @ W + b; LSTM cell; h -> combT (hi/lo) ----------------
// block: 16 n rows x 64 k at fixed b. thread (k=t&63, q=t>>6) handles 4 n rows.
template<int CCH>
__global__ __launch_bounds__(256) void cell_update_T(
        const float* __restrict__ conv, int convStride,
        const float* __restrict__ W, const float* __restrict__ bias,
        float* __restrict__ cbuf,
        short* __restrict__ dAhi, short* __restrict__ dAlo, int CDa, int offa,
        short* __restrict__ dBhi, short* __restrict__ dBlo, int CDb, int offb) {
    __shared__ float strans[64][17];
    const int t = threadIdx.x;
    const int b = blockIdx.y;
    const int n0 = blockIdx.x * 16;
    const int k = t & 63, q = t >> 6;

    float acc[4][4] = {};
    const float* cp = conv + (size_t)(n0 + q*4)*convStride + b*CCH;
    const float* Wk = W + k;
    for (int c = 0; c < CCH; c += 2) {
        float2 v0 = *(const float2*)(cp + c);
        float2 v1 = *(const float2*)(cp + (size_t)convStride + c);
        float2 v2 = *(const float2*)(cp + 2*(size_t)convStride + c);
        float2 v3 = *(const float2*)(cp + 3*(size_t)convStride + c);
        float wA[4], wB[4];
#pragma unroll
        for (int g = 0; g < 4; ++g) {
            wA[g] = Wk[(size_t)c*256 + g*64];
            wB[g] = Wk[(size_t)(c+1)*256 + g*64];
        }
#pragma unroll
        for (int g = 0; g < 4; ++g) {
            acc[0][g] = fmaf(v0.y, wB[g], fmaf(v0.x, wA[g], acc[0][g]));
            acc[1][g] = fmaf(v1.y, wB[g], fmaf(v1.x, wA[g], acc[1][g]));
            acc[2][g] = fmaf(v2.y, wB[g], fmaf(v2.x, wA[g], acc[2][g]));
            acc[3][g] = fmaf(v3.y, wB[g], fmaf(v3.x, wA[g], acc[3][g]));
        }
    }
    const float bi = bias[k], bfg = bias[64+k], bg = bias[128+k], bo = bias[192+k];
#pragma unroll
    for (int r = 0; r < 4; ++r) {
        int n = n0 + q*4 + r;
        float gi = 1.f/(1.f + expf(-(acc[r][0] + bi)));
        float gf = 1.f/(1.f + expf(-(acc[r][1] + bfg)));
        float gg = tanhf(acc[r][2] + bg);
        float go = 1.f/(1.f + expf(-(acc[r][3] + bo)));
        size_t ci = ((size_t)n*BB + b)*HH + k;
        float cold = cbuf[ci];
        float cnew = gf*cold + gi*gg;
        cbuf[ci] = cnew;
        strans[k][q*4 + r] = go * tanhf(cnew);
    }
    __syncthreads();
    // write-out: thread t -> dest d = t>>6 (0:Ahi 1:Alo 2:Bhi 3:Blo), row kk = t&63
    const int kk = t & 63, d = t >> 6;
    short* dst; int CD, off;
    const bool isLo = d & 1;
    if (d < 2) { dst = isLo ? dAlo : dAhi; CD = CDa; off = offa; }
    else       { dst = isLo ? dBlo : dBhi; CD = CDb; off = offb; }
    if (dst) {
        short tmp[16];
#pragma unroll
        for (int i = 0; i < 16; ++i) {
            float h = strans[kk][i];
            short hi = f2bf(h);
            tmp[i] = isLo ? f2bf(h - bf2f(hi)) : hi;
        }
        short* p = dst + (size_t)(b*CD + off + kk)*NN + n0;
        *(uint4*)p       = *(const uint4*)tmp;
        *(uint4*)(p + 8) = *(const uint4*)(tmp + 8);
    }
}

// ---------------- out = h2 @ Wp + bp, [B,HOR,N,1] ----------------
__global__ __launch_bounds__(256) void proj_T(const short* __restrict__ h2hi,
        const short* __restrict__ h2lo, const float* __restrict__ Wp,
        const float* __restrict__ bp, float* __restrict__ out) {
    __shared__ float sW[HH*HOR];
    __shared__ float sb[HOR];
    for (int i = threadIdx.x; i < HH*HOR; i += 256) sW[i] = Wp[i];
    if (threadIdx.x < HOR) sb[threadIdx.x] = bp[threadIdx.x];
    __syncthreads();
    int idx = blockIdx.x*256 + threadIdx.x;    // b*2048 + n
    int b = idx >> 11, n = idx & (NN-1);
    float acc[HOR];
#pragma unroll
    for (int j = 0; j < HOR; ++j) acc[j] = sb[j];
    for (int k = 0; k < HH; ++k) {
        size_t row = (size_t)(b*C2 + HH + k)*NN + n;
        float h = bf2f(h2hi[row]) + bf2f(h2lo[row]);
#pragma unroll
        for (int j = 0; j < HOR; ++j) acc[j] = fmaf(h, sW[k*HOR + j], acc[j]);
    }
#pragma unroll
    for (int j = 0; j < HOR; ++j)
        out[(size_t)(b*HOR + j)*NN + n] = acc[j];
}

extern "C" void kernel_launch(void* const* d_in, const int* in_sizes, int n_in,
                              void* d_out, int out_size, void* d_ws, size_t ws_size,
                              hipStream_t stream) {
    const float* x  = (const float*)d_in[0];
    const float* E  = (const float*)d_in[1];
    const float* W1 = (const float*)d_in[2];
    const float* b1 = (const float*)d_in[3];
    const float* W2 = (const float*)d_in[4];
    const float* b2 = (const float*)d_in[5];
    const float* Wp = (const float*)d_in[6];
    const float* bp = (const float*)d_in[7];
    float* out = (float*)d_out;

    char* base = (char*)d_ws;
    short* Ahi   = (short*)base; base += (size_t)NN*NN*2;
    short* Alo   = (short*)base; base += (size_t)NN*NN*2;
    short* c1Thi = (short*)base; base += (size_t)COLS1P*NN*2;
    short* c1Tlo = (short*)base; base += (size_t)COLS1P*NN*2;
    short* c2Thi = (short*)base; base += (size_t)COLS2*NN*2;
    short* c2Tlo = (short*)base; base += (size_t)COLS2*NN*2;
    float* conv  = (float*)base; base += (size_t)NN*COLS2*4;
    float* cs1   = (float*)base; base += (size_t)NB*HH*4;
    float* cs2   = (float*)base; base += (size_t)NB*HH*4;

    // deterministic state init every call
    hipMemsetAsync(c1Thi, 0, (size_t)COLS1P*NN*2, stream);
    hipMemsetAsync(c1Tlo, 0, (size_t)COLS1P*NN*2, stream);
    hipMemsetAsync(c2Thi, 0, (size_t)COLS2*NN*2, stream);
    hipMemsetAsync(c2Tlo, 0, (size_t)COLS2*NN*2, stream);
    hipMemsetAsync(cs1,   0, (size_t)NB*HH*4, stream);
    hipMemsetAsync(cs2,   0, (size_t)NB*HH*4, stream);

    compute_A_kernel<<<NN, 256, 0, stream>>>(E, Ahi, Alo);

    for (int t = 0; t < TT; ++t) {
        scatter_xT_kernel<<<(BB*NN*CIN + 255)/256, 256, 0, stream>>>(x, c1Thi, c1Tlo, t);
        // layer 1: conv = A @ [x_t, h1]   (cols padded 2112 -> 2176)
        gc_gemm_bf16<64><<<dim3(COLS1P/64, NN/128), 256, 0, stream>>>(
            Ahi, Alo, c1Thi, c1Tlo, conv, COLS1P);
        cell_update_T<C1><<<dim3(NN/16, BB), 256, 0, stream>>>(
            conv, COLS1P, W1, b1, cs1,
            c1Thi, c1Tlo, C1, CIN,       // h1 -> comb1T c=2..65
            c2Thi, c2Tlo, C2, 0);        // h1 -> comb2T c=0..63
        // layer 2: conv = A @ [h1, h2]
        gc_gemm_bf16<128><<<dim3(COLS2/128, NN/128), 256, 0, stream>>>(
            Ahi, Alo, c2Thi, c2Tlo, conv, COLS2);
        cell_update_T<C2><<<dim3(NN/16, BB), 256, 0, stream>>>(
            conv, COLS2, W2, b2, cs2,
            c2Thi, c2Tlo, C2, HH,        // h2 -> comb2T c=64..127
            nullptr, nullptr, 0, 0);
    }
    proj_T<<<(BB*NN + 255)/256, 256, 0, stream>>>(c2Thi, c2Tlo, Wp, bp, out);
}

// Round 3
// 7764.231 us; speedup vs baseline: 2.8491x; 1.4380x over previous
//
#include <hip/hip_runtime.h>
#include <hip/hip_bf16.h>
#include <cstddef>
#include <cstdint>

#define NN   2048
#define BB   32
#define TT   24
#define CIN  2
#define HH   64
#define EMBD 16
#define HOR  12
#define XC   (TT*BB*CIN)   // 1536 cols of precomputed A@x
#define NB   (NN*BB)

using bfrag = __attribute__((ext_vector_type(8))) short;   // 8 bf16 = 4 VGPR
using f32x4 = __attribute__((ext_vector_type(4))) float;

static __device__ __forceinline__ short f2bf(float f) {
    __hip_bfloat16 h = __float2bfloat16(f);
    return *reinterpret_cast<short*>(&h);
}
static __device__ __forceinline__ float bf2f(short s) {
    __hip_bfloat16 h;
    *reinterpret_cast<short*>(&h) = s;
    return __bfloat162float(h);
}

#define AS1 __attribute__((address_space(1)))
#define AS3 __attribute__((address_space(3)))
static __device__ __forceinline__ void gload16(const short* g, short* l) {
    __builtin_amdgcn_global_load_lds((const AS1 void*)g, (AS3 void*)l, 16, 0, 0);
}

// ---------------- A = softmax(relu(E E^T)) -> split bf16 hi/lo ----------------
__global__ __launch_bounds__(256) void compute_A_kernel(const float* __restrict__ E,
                                                        short* __restrict__ Ahi,
                                                        short* __restrict__ Alo) {
    __shared__ float srow[NN];
    __shared__ float sred[256];
    int row = blockIdx.x;
    float er[EMBD];
#pragma unroll
    for (int k = 0; k < EMBD; ++k) er[k] = E[row*EMBD + k];
    float lmax = -1e30f;
    for (int j = threadIdx.x; j < NN; j += 256) {
        const float* ej = E + j*EMBD;
        float d = 0.f;
#pragma unroll
        for (int k = 0; k < EMBD; ++k) d = fmaf(er[k], ej[k], d);
        d = fmaxf(d, 0.f);
        srow[j] = d;
        lmax = fmaxf(lmax, d);
    }
    sred[threadIdx.x] = lmax;
    __syncthreads();
    for (int s = 128; s > 0; s >>= 1) {
        if (threadIdx.x < s) sred[threadIdx.x] = fmaxf(sred[threadIdx.x], sred[threadIdx.x+s]);
        __syncthreads();
    }
    float rmax = sred[0];
    __syncthreads();
    float lsum = 0.f;
    for (int j = threadIdx.x; j < NN; j += 256) {
        float e = expf(srow[j] - rmax);
        srow[j] = e;
        lsum += e;
    }
    sred[threadIdx.x] = lsum;
    __syncthreads();
    for (int s = 128; s > 0; s >>= 1) {
        if (threadIdx.x < s) sred[threadIdx.x] += sred[threadIdx.x+s];
        __syncthreads();
    }
    float rinv = 1.f / sred[0];
    for (int j = threadIdx.x; j < NN; j += 256) {
        float v = srow[j] * rinv;
        short h = f2bf(v);
        Ahi[(size_t)row*NN + j] = h;
        Alo[(size_t)row*NN + j] = f2bf(v - bf2f(h));
    }
}

// ---------------- build XallT hi/lo: [col=(t*32+b)*2+c][n] ----------------
__global__ void scatter_xall(const float* __restrict__ x,
                             short* __restrict__ hi, short* __restrict__ lo) {
    int idx = blockIdx.x*256 + threadIdx.x;     // col*2048 + n
    int n = idx & (NN-1);
    int col = idx >> 11;
    int c = col & 1, b = (col >> 1) & 31, t = col >> 6;
    float v = x[(size_t)(((size_t)b*TT + t)*NN + n)*CIN + c];
    short h = f2bf(v);
    size_t o = (size_t)col*NN + n;
    hi[o] = h;
    lo[o] = f2bf(v - bf2f(h));
}

// ---------------- C = A @ B^T via fused 3-term split-bf16 MFMA ----------------
// Ahi/Alo: [2048 rows][2048 K] bf16; Bhi/Blo: [cols][2048 K] bf16 ("B^T input")
// Cout: [2048 rows][outStride] f32.  Tile: 64 rows x 128 cols, 4 waves (2x2).
// LDS XOR-swizzle: within each 2-row pair (128B), chunk q ^= (rowpair&7);
// staged via pre-swizzled global source (linear global_load_lds dest).
__global__ __launch_bounds__(256, 3) void gc3_gemm(
        const short* __restrict__ Ahi, const short* __restrict__ Alo,
        const short* __restrict__ Bhi, const short* __restrict__ Blo,
        float* __restrict__ Cout, int outStride) {
    __shared__ short As[12288];    // AsHi[2048] AsLo[2048] BsHi[4096] BsLo[4096]
    short* AsHi = As;
    short* AsLo = As + 2048;
    short* BsHi = As + 4096;
    short* BsLo = As + 8192;
    const int t = threadIdx.x;
    const int w = t >> 6, lane = t & 63;
    const int wm = w >> 1, wn = w & 1;
    const int fr = lane & 15, fc = lane >> 4;
    const int rowbase = blockIdx.y * 64;
    const int colbase = blockIdx.x * 128;

    // staging source decode (pre-swizzled so linear LDS dest lands swizzled)
    const int rp = t >> 3, ql = t & 7;
    const int qs = ql ^ (rp & 7);
    const int srow = rp*2 + (qs >> 2);
    const int sch  = (qs & 3) * 8;
    const short* aHiS = Ahi + (size_t)(rowbase + srow)*NN + sch;
    const short* aLoS = Alo + (size_t)(rowbase + srow)*NN + sch;
    const short* bHiS = Bhi + (size_t)(colbase + srow)*NN + sch;
    const short* bLoS = Blo + (size_t)(colbase + srow)*NN + sch;
    const size_t bHalf = (size_t)64*NN;

    short* aHiD  = AsHi + t*8;
    short* aLoD  = AsLo + t*8;
    short* bHiD0 = BsHi + t*8;
    short* bHiD1 = BsHi + 2048 + t*8;
    short* bLoD0 = BsLo + t*8;
    short* bLoD1 = BsLo + 2048 + t*8;

    // swizzled fragment read offsets (shorts), loop-invariant
    auto ldsoff = [](int row, int f) {
        int rr = row >> 1;
        int q = (((row & 1) << 2) | f) ^ (rr & 7);
        return rr*64 + q*8;
    };
    int aoff[2], boff[4];
#pragma unroll
    for (int m = 0; m < 2; ++m) aoff[m] = ldsoff(wm*32 + m*16 + fr, fc);
#pragma unroll
    for (int n = 0; n < 4; ++n) boff[n] = ldsoff(wn*64 + n*16 + fr, fc);

    f32x4 acc[2][4];
#pragma unroll
    for (int m = 0; m < 2; ++m)
#pragma unroll
        for (int n = 0; n < 4; ++n)
#pragma unroll
            for (int r = 0; r < 4; ++r) acc[m][n][r] = 0.f;

    for (int k0 = 0; k0 < NN; k0 += 32) {
        gload16(aHiS, aHiD);
        gload16(aLoS, aLoD);
        gload16(bHiS, bHiD0);
        gload16(bHiS + bHalf, bHiD1);
        gload16(bLoS, bLoD0);
        gload16(bLoS + bHalf, bLoD1);
        aHiS += 32; aLoS += 32; bHiS += 32; bLoS += 32;
        __syncthreads();
        bfrag ah[2], al[2], bh[4], bl[4];
#pragma unroll
        for (int m = 0; m < 2; ++m) {
            ah[m] = *(const bfrag*)(AsHi + aoff[m]);
            al[m] = *(const bfrag*)(AsLo + aoff[m]);
        }
#pragma unroll
        for (int n = 0; n < 4; ++n) {
            bh[n] = *(const bfrag*)(BsHi + boff[n]);
            bl[n] = *(const bfrag*)(BsLo + boff[n]);
        }
#pragma unroll
        for (int m = 0; m < 2; ++m)
#pragma unroll
            for (int n = 0; n < 4; ++n) {
                acc[m][n] = __builtin_amdgcn_mfma_f32_16x16x32_bf16(ah[m], bh[n], acc[m][n], 0, 0, 0);
                acc[m][n] = __builtin_amdgcn_mfma_f32_16x16x32_bf16(ah[m], bl[n], acc[m][n], 0, 0, 0);
                acc[m][n] = __builtin_amdgcn_mfma_f32_16x16x32_bf16(al[m], bh[n], acc[m][n], 0, 0, 0);
            }
        __syncthreads();
    }
    // C/D layout: col = lane&15, row = (lane>>4)*4 + reg
#pragma unroll
    for (int m = 0; m < 2; ++m) {
        const int gr = rowbase + wm*32 + m*16 + fc*4;
#pragma unroll
        for (int n = 0; n < 4; ++n) {
            const int gc = colbase + wn*64 + n*16 + fr;
#pragma unroll
            for (int r = 0; r < 4; ++r)
                Cout[(size_t)(gr + r)*outStride + gc] = acc[m][n][r];
        }
    }
}

// ---------------- cell 1: gates = convX_t@Wx + P1prev@Wh + b; writes h1T ----------------
__global__ __launch_bounds__(256) void cell1_kernel(
        const float* __restrict__ convX, const float* __restrict__ Pp,
        const float* __restrict__ W, const float* __restrict__ bias,
        float* __restrict__ cbuf,
        short* __restrict__ hThi, short* __restrict__ hTlo, int tstep) {
    __shared__ float strans[64][17];
    const int t = threadIdx.x;
    const int b = blockIdx.y;
    const int n0 = blockIdx.x * 16;
    const int k = t & 63, q = t >> 6;
    float acc[4][4] = {};
    const float* pr = Pp + (size_t)(n0 + q*4)*NN + b*64;
    for (int c0 = 0; c0 < 64; c0 += 4) {
        float4 v0 = *(const float4*)(pr + c0);
        float4 v1 = *(const float4*)(pr + NN + c0);
        float4 v2 = *(const float4*)(pr + 2*NN + c0);
        float4 v3 = *(const float4*)(pr + 3*NN + c0);
#pragma unroll
        for (int dc = 0; dc < 4; ++dc) {
            const float* wp = W + (size_t)(2 + c0 + dc)*256 + k;
            float w0 = wp[0], w1 = wp[64], w2 = wp[128], w3 = wp[192];
            float p0 = ((const float*)&v0)[dc];
            float p1 = ((const float*)&v1)[dc];
            float p2 = ((const float*)&v2)[dc];
            float p3 = ((const float*)&v3)[dc];
            acc[0][0] = fmaf(p0, w0, acc[0][0]); acc[0][1] = fmaf(p0, w1, acc[0][1]);
            acc[0][2] = fmaf(p0, w2, acc[0][2]); acc[0][3] = fmaf(p0, w3, acc[0][3]);
            acc[1][0] = fmaf(p1, w0, acc[1][0]); acc[1][1] = fmaf(p1, w1, acc[1][1]);
            acc[1][2] = fmaf(p1, w2, acc[1][2]); acc[1][3] = fmaf(p1, w3, acc[1][3]);
            acc[2][0] = fmaf(p2, w0, acc[2][0]); acc[2][1] = fmaf(p2, w1, acc[2][1]);
            acc[2][2] = fmaf(p2, w2, acc[2][2]); acc[2][3] = fmaf(p2, w3, acc[2][3]);
            acc[3][0] = fmaf(p3, w0, acc[3][0]); acc[3][1] = fmaf(p3, w1, acc[3][1]);
            acc[3][2] = fmaf(p3, w2, acc[3][2]); acc[3][3] = fmaf(p3, w3, acc[3][3]);
        }
    }
    // x contribution (2 channels)
    const float* cx = convX + (size_t)(n0 + q*4)*XC + tstep*64 + b*2;
#pragma unroll
    for (int r = 0; r < 4; ++r) {
#pragma unroll
        for (int c = 0; c < 2; ++c) {
            float xv = cx[(size_t)r*XC + c];
            const float* wp = W + (size_t)c*256 + k;
            acc[r][0] = fmaf(xv, wp[0],   acc[r][0]);
            acc[r][1] = fmaf(xv, wp[64],  acc[r][1]);
            acc[r][2] = fmaf(xv, wp[128], acc[r][2]);
            acc[r][3] = fmaf(xv, wp[192], acc[r][3]);
        }
    }
    const float bi = bias[k], bfg = bias[64+k], bg = bias[128+k], bo = bias[192+k];
#pragma unroll
    for (int r = 0; r < 4; ++r) {
        int n = n0 + q*4 + r;
        float gi = 1.f/(1.f + expf(-(acc[r][0] + bi)));
        float gf = 1.f/(1.f + expf(-(acc[r][1] + bfg)));
        float gg = tanhf(acc[r][2] + bg);
        float go = 1.f/(1.f + expf(-(acc[r][3] + bo)));
        size_t ci = ((size_t)n*BB + b)*HH + k;
        float cold = cbuf[ci];
        float cnew = gf*cold + gi*gg;
        cbuf[ci] = cnew;
        strans[k][q*4 + r] = go * tanhf(cnew);
    }
    __syncthreads();
    // write h^T: rows (b*64+kk), 16 n-cols; 256 threads = 64 kk x {hi,lo} x 2 n-halves
    const int kk = t & 63, d = (t >> 6) & 1, half = t >> 7;
    short tmp[8];
#pragma unroll
    for (int i = 0; i < 8; ++i) {
        float h = strans[kk][half*8 + i];
        short hb = f2bf(h);
        tmp[i] = d ? f2bf(h - bf2f(hb)) : hb;
    }
    short* dst = (d ? hTlo : hThi) + (size_t)(b*64 + kk)*NN + n0 + half*8;
    *(uint4*)dst = *(const uint4*)tmp;
}

// ---------------- cell 2: gates = P1cur@Wa + P2prev@Wb + b; writes h2T ----------------
__global__ __launch_bounds__(256) void cell2_kernel(
        const float* __restrict__ P1c, const float* __restrict__ P2p,
        const float* __restrict__ W, const float* __restrict__ bias,
        float* __restrict__ cbuf,
        short* __restrict__ hThi, short* __restrict__ hTlo) {
    __shared__ float strans[64][17];
    const int t = threadIdx.x;
    const int b = blockIdx.y;
    const int n0 = blockIdx.x * 16;
    const int k = t & 63, q = t >> 6;
    float acc[4][4] = {};
    const float* p1 = P1c + (size_t)(n0 + q*4)*NN + b*64;
    const float* p2 = P2p + (size_t)(n0 + q*4)*NN + b*64;
    for (int src = 0; src < 2; ++src) {
        const float* pr = src ? p2 : p1;
        const float* Wb = W + (size_t)(src ? 64 : 0)*256;
        for (int c0 = 0; c0 < 64; c0 += 4) {
            float4 v0 = *(const float4*)(pr + c0);
            float4 v1 = *(const float4*)(pr + NN + c0);
            float4 v2 = *(const float4*)(pr + 2*NN + c0);
            float4 v3 = *(const float4*)(pr + 3*NN + c0);
#pragma unroll
            for (int dc = 0; dc < 4; ++dc) {
                const float* wp = Wb + (size_t)(c0 + dc)*256 + k;
                float w0 = wp[0], w1 = wp[64], w2 = wp[128], w3 = wp[192];
                float p0v = ((const float*)&v0)[dc];
                float p1v = ((const float*)&v1)[dc];
                float p2v = ((const float*)&v2)[dc];
                float p3v = ((const float*)&v3)[dc];
                acc[0][0] = fmaf(p0v, w0, acc[0][0]); acc[0][1] = fmaf(p0v, w1, acc[0][1]);
                acc[0][2] = fmaf(p0v, w2, acc[0][2]); acc[0][3] = fmaf(p0v, w3, acc[0][3]);
                acc[1][0] = fmaf(p1v, w0, acc[1][0]); acc[1][1] = fmaf(p1v, w1, acc[1][1]);
                acc[1][2] = fmaf(p1v, w2, acc[1][2]); acc[1][3] = fmaf(p1v, w3, acc[1][3]);
                acc[2][0] = fmaf(p2v, w0, acc[2][0]); acc[2][1] = fmaf(p2v, w1, acc[2][1]);
                acc[2][2] = fmaf(p2v, w2, acc[2][2]); acc[2][3] = fmaf(p2v, w3, acc[2][3]);
                acc[3][0] = fmaf(p3v, w0, acc[3][0]); acc[3][1] = fmaf(p3v, w1, acc[3][1]);
                acc[3][2] = fmaf(p3v, w2, acc[3][2]); acc[3][3] = fmaf(p3v, w3, acc[3][3]);
            }
        }
    }
    const float bi = bias[k], bfg = bias[64+k], bg = bias[128+k], bo = bias[192+k];
#pragma unroll
    for (int r = 0; r < 4; ++r) {
        int n = n0 + q*4 + r;
        float gi = 1.f/(1.f + expf(-(acc[r][0] + bi)));
        float gf = 1.f/(1.f + expf(-(acc[r][1] + bfg)));
        float gg = tanhf(acc[r][2] + bg);
        float go = 1.f/(1.f + expf(-(acc[r][3] + bo)));
        size_t ci = ((size_t)n*BB + b)*HH + k;
        float cold = cbuf[ci];
        float cnew = gf*cold + gi*gg;
        cbuf[ci] = cnew;
        strans[k][q*4 + r] = go * tanhf(cnew);
    }
    __syncthreads();
    const int kk = t & 63, d = (t >> 6) & 1, half = t >> 7;
    short tmp[8];
#pragma unroll
    for (int i = 0; i < 8; ++i) {
        float h = strans[kk][half*8 + i];
        short hb = f2bf(h);
        tmp[i] = d ? f2bf(h - bf2f(hb)) : hb;
    }
    short* dst = (d ? hTlo : hThi) + (size_t)(b*64 + kk)*NN + n0 + half*8;
    *(uint4*)dst = *(const uint4*)tmp;
}

// ---------------- out = h2 @ Wp + bp -> [B,HOR,N,1] ----------------
__global__ __launch_bounds__(256) void proj_T(const short* __restrict__ h2hi,
        const short* __restrict__ h2lo, const float* __restrict__ Wp,
        const float* __restrict__ bp, float* __restrict__ out) {
    __shared__ float sW[HH*HOR];
    __shared__ float sb[HOR];
    for (int i = threadIdx.x; i < HH*HOR; i += 256) sW[i] = Wp[i];
    if (threadIdx.x < HOR) sb[threadIdx.x] = bp[threadIdx.x];
    __syncthreads();
    int idx = blockIdx.x*256 + threadIdx.x;    // b*2048 + n
    int b = idx >> 11, n = idx & (NN-1);
    float acc[HOR];
#pragma unroll
    for (int j = 0; j < HOR; ++j) acc[j] = sb[j];
    for (int k = 0; k < HH; ++k) {
        size_t row = (size_t)(b*64 + k)*NN + n;
        float h = bf2f(h2hi[row]) + bf2f(h2lo[row]);
#pragma unroll
        for (int j = 0; j < HOR; ++j) acc[j] = fmaf(h, sW[k*HOR + j], acc[j]);
    }
#pragma unroll
    for (int j = 0; j < HOR; ++j)
        out[(size_t)(b*HOR + j)*NN + n] = acc[j];
}

extern "C" void kernel_launch(void* const* d_in, const int* in_sizes, int n_in,
                              void* d_out, int out_size, void* d_ws, size_t ws_size,
                              hipStream_t stream) {
    const float* x  = (const float*)d_in[0];
    const float* E  = (const float*)d_in[1];
    const float* W1 = (const float*)d_in[2];
    const float* b1 = (const float*)d_in[3];
    const float* W2 = (const float*)d_in[4];
    const float* b2 = (const float*)d_in[5];
    const float* Wp = (const float*)d_in[6];
    const float* bp = (const float*)d_in[7];
    float* out = (float*)d_out;

    char* base = (char*)d_ws;
    short* Ahi   = (short*)base; base += (size_t)NN*NN*2;      // 8.39M
    short* Alo   = (short*)base; base += (size_t)NN*NN*2;      // 8.39M
    float* convX = (float*)base; base += (size_t)NN*XC*4;      // 12.58M
    float* P1    = (float*)base; base += (size_t)NN*NN*4;      // 16.78M
    float* P2    = (float*)base; base += (size_t)NN*NN*4;      // 16.78M
    short* h1Thi = (short*)base; base += (size_t)NN*NN*2;
    short* h1Tlo = (short*)base; base += (size_t)NN*NN*2;
    short* h2Thi = (short*)base; base += (size_t)NN*NN*2;
    short* h2Tlo = (short*)base; base += (size_t)NN*NN*2;
    float* cs1   = (float*)base; base += (size_t)NB*HH*4;      // 16.78M
    float* cs2   = (float*)base; base += (size_t)NB*HH*4;      // 16.78M
    // XallT aliases P2 (consumed by convX GEMM before P2 is zeroed)
    short* XThi = (short*)P2;
    short* XTlo = XThi + (size_t)XC*NN;

    hipMemsetAsync(P1,  0, (size_t)NN*NN*4, stream);
    hipMemsetAsync(cs1, 0, (size_t)NB*HH*4, stream);
    hipMemsetAsync(cs2, 0, (size_t)NB*HH*4, stream);

    compute_A_kernel<<<NN, 256, 0, stream>>>(E, Ahi, Alo);
    scatter_xall<<<(XC*NN)/256, 256, 0, stream>>>(x, XThi, XTlo);
    // convX = A @ Xall  (once, all timesteps)
    gc3_gemm<<<dim3(XC/128, NN/64), 256, 0, stream>>>(Ahi, Alo, XThi, XTlo, convX, XC);
    // now XT region is dead -> zero P2 for first-step read
    hipMemsetAsync(P2, 0, (size_t)NN*NN*4, stream);

    for (int t = 0; t < TT; ++t) {
        cell1_kernel<<<dim3(NN/16, BB), 256, 0, stream>>>(
            convX, P1, W1, b1, cs1, h1Thi, h1Tlo, t);
        gc3_gemm<<<dim3(NN/128, NN/64), 256, 0, stream>>>(
            Ahi, Alo, h1Thi, h1Tlo, P1, NN);
        cell2_kernel<<<dim3(NN/16, BB), 256, 0, stream>>>(
            P1, P2, W2, b2, cs2, h2Thi, h2Tlo);
        if (t < TT-1)
            gc3_gemm<<<dim3(NN/128, NN/64), 256, 0, stream>>>(
                Ahi, Alo, h2Thi, h2Tlo, P2, NN);
    }
    proj_T<<<(BB*NN)/256, 256, 0, stream>>>(h2Thi, h2Tlo, Wp, bp, out);
}

// Round 4
// 4795.304 us; speedup vs baseline: 4.6130x; 1.6191x over previous
//
#include <hip/hip_runtime.h>
#include <hip/hip_bf16.h>
#include <cstddef>
#include <cstdint>

#define NN   2048
#define BB   32
#define TT   24
#define CIN  2
#define HH   64
#define EMBD 16
#define HOR  12
#define XC   (TT*BB*CIN)   // 1536 cols of precomputed A@x
#define PW   4096          // P row width: cols [0,2048)=P2, [2048,4096)=P1

using bfrag = __attribute__((ext_vector_type(8))) short;   // 8 bf16 = 4 VGPR
using f32x4 = __attribute__((ext_vector_type(4))) float;

static __device__ __forceinline__ short f2bf(float f) {
    __hip_bfloat16 h = __float2bfloat16(f);
    return *reinterpret_cast<short*>(&h);
}
static __device__ __forceinline__ float bf2f(short s) {
    __hip_bfloat16 h;
    *reinterpret_cast<short*>(&h) = s;
    return __bfloat162float(h);
}

#define AS1 __attribute__((address_space(1)))
#define AS3 __attribute__((address_space(3)))
static __device__ __forceinline__ void gload16(const short* g, short* l) {
    __builtin_amdgcn_global_load_lds((const AS1 void*)g, (AS3 void*)l, 16, 0, 0);
}

// ---------------- A = softmax(relu(E E^T)) -> split bf16 hi/lo ----------------
__global__ __launch_bounds__(256) void compute_A_kernel(const float* __restrict__ E,
                                                        short* __restrict__ Ahi,
                                                        short* __restrict__ Alo) {
    __shared__ float srow[NN];
    __shared__ float sred[256];
    int row = blockIdx.x;
    float er[EMBD];
#pragma unroll
    for (int k = 0; k < EMBD; ++k) er[k] = E[row*EMBD + k];
    float lmax = -1e30f;
    for (int j = threadIdx.x; j < NN; j += 256) {
        const float* ej = E + j*EMBD;
        float d = 0.f;
#pragma unroll
        for (int k = 0; k < EMBD; ++k) d = fmaf(er[k], ej[k], d);
        d = fmaxf(d, 0.f);
        srow[j] = d;
        lmax = fmaxf(lmax, d);
    }
    sred[threadIdx.x] = lmax;
    __syncthreads();
    for (int s = 128; s > 0; s >>= 1) {
        if (threadIdx.x < s) sred[threadIdx.x] = fmaxf(sred[threadIdx.x], sred[threadIdx.x+s]);
        __syncthreads();
    }
    float rmax = sred[0];
    __syncthreads();
    float lsum = 0.f;
    for (int j = threadIdx.x; j < NN; j += 256) {
        float e = expf(srow[j] - rmax);
        srow[j] = e;
        lsum += e;
    }
    sred[threadIdx.x] = lsum;
    __syncthreads();
    for (int s = 128; s > 0; s >>= 1) {
        if (threadIdx.x < s) sred[threadIdx.x] += sred[threadIdx.x+s];
        __syncthreads();
    }
    float rinv = 1.f / sred[0];
    for (int j = threadIdx.x; j < NN; j += 256) {
        float v = srow[j] * rinv;
        short h = f2bf(v);
        Ahi[(size_t)row*NN + j] = h;
        Alo[(size_t)row*NN + j] = f2bf(v - bf2f(h));
    }
}

// ---------------- build XallT hi/lo: [col=(t*32+b)*2+c][n] ----------------
__global__ void scatter_xall(const float* __restrict__ x,
                             short* __restrict__ hi, short* __restrict__ lo) {
    int idx = blockIdx.x*256 + threadIdx.x;     // col*2048 + n
    int n = idx & (NN-1);
    int col = idx >> 11;
    int c = col & 1, b = (col >> 1) & 31, t = col >> 6;
    float v = x[(size_t)(((size_t)b*TT + t)*NN + n)*CIN + c];
    short h = f2bf(v);
    size_t o = (size_t)col*NN + n;
    hi[o] = h;
    lo[o] = f2bf(v - bf2f(h));
}

// ---------------- W^T split: Wt[j][c] = split(W[rowoff+c][j]) ----------------
__global__ void wsplit_T(const float* __restrict__ W, int rowoff, int Kd,
                         short* __restrict__ hi, short* __restrict__ lo) {
    int id = blockIdx.x*256 + threadIdx.x;      // j*Kd + c
    if (id >= 256*Kd) return;
    int j = id / Kd, c = id - j*Kd;
    float v = W[(size_t)(rowoff + c)*256 + j];
    short h = f2bf(v);
    hi[id] = h;
    lo[id] = f2bf(v - bf2f(h));
}

// ---------------- C = A @ B^T via fused 3-term split-bf16 MFMA ----------------
// (proven round-3 kernel, unchanged)
__global__ __launch_bounds__(256, 3) void gc3_gemm(
        const short* __restrict__ Ahi, const short* __restrict__ Alo,
        const short* __restrict__ Bhi, const short* __restrict__ Blo,
        float* __restrict__ Cout, int outStride) {
    __shared__ short As[12288];
    short* AsHi = As;
    short* AsLo = As + 2048;
    short* BsHi = As + 4096;
    short* BsLo = As + 8192;
    const int t = threadIdx.x;
    const int w = t >> 6, lane = t & 63;
    const int wm = w >> 1, wn = w & 1;
    const int fr = lane & 15, fc = lane >> 4;
    const int rowbase = blockIdx.y * 64;
    const int colbase = blockIdx.x * 128;

    const int rp = t >> 3, ql = t & 7;
    const int qs = ql ^ (rp & 7);
    const int srow = rp*2 + (qs >> 2);
    const int sch  = (qs & 3) * 8;
    const short* aHiS = Ahi + (size_t)(rowbase + srow)*NN + sch;
    const short* aLoS = Alo + (size_t)(rowbase + srow)*NN + sch;
    const short* bHiS = Bhi + (size_t)(colbase + srow)*NN + sch;
    const short* bLoS = Blo + (size_t)(colbase + srow)*NN + sch;
    const size_t bHalf = (size_t)64*NN;

    short* aHiD  = AsHi + t*8;
    short* aLoD  = AsLo + t*8;
    short* bHiD0 = BsHi + t*8;
    short* bHiD1 = BsHi + 2048 + t*8;
    short* bLoD0 = BsLo + t*8;
    short* bLoD1 = BsLo + 2048 + t*8;

    auto ldsoff = [](int row, int f) {
        int rr = row >> 1;
        int q = (((row & 1) << 2) | f) ^ (rr & 7);
        return rr*64 + q*8;
    };
    int aoff[2], boff[4];
#pragma unroll
    for (int m = 0; m < 2; ++m) aoff[m] = ldsoff(wm*32 + m*16 + fr, fc);
#pragma unroll
    for (int n = 0; n < 4; ++n) boff[n] = ldsoff(wn*64 + n*16 + fr, fc);

    f32x4 acc[2][4];
#pragma unroll
    for (int m = 0; m < 2; ++m)
#pragma unroll
        for (int n = 0; n < 4; ++n)
#pragma unroll
            for (int r = 0; r < 4; ++r) acc[m][n][r] = 0.f;

    for (int k0 = 0; k0 < NN; k0 += 32) {
        gload16(aHiS, aHiD);
        gload16(aLoS, aLoD);
        gload16(bHiS, bHiD0);
        gload16(bHiS + bHalf, bHiD1);
        gload16(bLoS, bLoD0);
        gload16(bLoS + bHalf, bLoD1);
        aHiS += 32; aLoS += 32; bHiS += 32; bLoS += 32;
        __syncthreads();
        bfrag ah[2], al[2], bh[4], bl[4];
#pragma unroll
        for (int m = 0; m < 2; ++m) {
            ah[m] = *(const bfrag*)(AsHi + aoff[m]);
            al[m] = *(const bfrag*)(AsLo + aoff[m]);
        }
#pragma unroll
        for (int n = 0; n < 4; ++n) {
            bh[n] = *(const bfrag*)(BsHi + boff[n]);
            bl[n] = *(const bfrag*)(BsLo + boff[n]);
        }
#pragma unroll
        for (int m = 0; m < 2; ++m)
#pragma unroll
            for (int n = 0; n < 4; ++n) {
                acc[m][n] = __builtin_amdgcn_mfma_f32_16x16x32_bf16(ah[m], bh[n], acc[m][n], 0, 0, 0);
                acc[m][n] = __builtin_amdgcn_mfma_f32_16x16x32_bf16(ah[m], bl[n], acc[m][n], 0, 0, 0);
                acc[m][n] = __builtin_amdgcn_mfma_f32_16x16x32_bf16(al[m], bh[n], acc[m][n], 0, 0, 0);
            }
        __syncthreads();
    }
#pragma unroll
    for (int m = 0; m < 2; ++m) {
        const int gr = rowbase + wm*32 + m*16 + fc*4;
#pragma unroll
        for (int n = 0; n < 4; ++n) {
            const int gc = colbase + wn*64 + n*16 + fr;
#pragma unroll
            for (int r = 0; r < 4; ++r)
                Cout[(size_t)(gr + r)*outStride + gc] = acc[m][n][r];
        }
    }
}

// ---------------- MFMA LSTM cell: gates = P-slices @ W^T; lane-local update ----
// Wave w owns j-tiles {g*4+w : g=0..3} -> lane holds all 4 gates for
// (n = n0 + (lane>>4)*4 + r, k = w*16 + (lane&15)). No LDS, no barriers.
// NCH=4 (cell2): chunks 0,1 from P1 (cols 2048+b*64+..), 2,3 from P2 (b*64+..)
// NCH=2 (cell1): chunks 0,1 from P1; XEP adds the 2-channel x contribution.
template<int NCH, bool XEP>
__global__ __launch_bounds__(256, 2) void cell_mfma(
        const float* __restrict__ P,
        const float* __restrict__ convX,
        const float* __restrict__ Wx,
        const short* __restrict__ Wthi, const short* __restrict__ Wtlo,
        const float* __restrict__ bias,
        float* __restrict__ cbuf,
        short* __restrict__ hThi, short* __restrict__ hTlo,
        int tstep) {
    const int t = threadIdx.x;
    const int w = t >> 6, lane = t & 63;
    const int fr = lane & 15, fc = lane >> 4;
    const int b = blockIdx.y;
    const int n0blk = blockIdx.x * 128;
    constexpr int KW = NCH*32;

    // persistent W^T fragments (hi/lo), loaded once
    bfrag bh[4][NCH], bl[4][NCH];
#pragma unroll
    for (int g = 0; g < 4; ++g)
#pragma unroll
        for (int ch = 0; ch < NCH; ++ch) {
            size_t o = (size_t)((g*4 + w)*16 + fr)*KW + ch*32 + fc*8;
            bh[g][ch] = *(const bfrag*)(Wthi + o);
            bl[g][ch] = *(const bfrag*)(Wtlo + o);
        }
    const int k = w*16 + fr;
    float bs[4], wx0[4], wx1[4];
#pragma unroll
    for (int g = 0; g < 4; ++g) {
        bs[g] = bias[g*64 + k];
        if (XEP) { wx0[g] = Wx[g*64 + k]; wx1[g] = Wx[256 + g*64 + k]; }
    }
    int colb[NCH];
#pragma unroll
    for (int ch = 0; ch < NCH; ++ch)
        colb[ch] = (NCH == 2 || ch < 2) ? (2048 + b*64 + ch*32)
                                        : (b*64 + (ch-2)*32);
    const int cc = lane >> 4;
    const size_t srow = (size_t)(b*64 + k)*NN;

    for (int nt = 0; nt < 8; ++nt) {
        const int n0 = n0blk + nt*16;
        bfrag ah[NCH], al[NCH];
#pragma unroll
        for (int ch = 0; ch < NCH; ++ch) {
            const float* ap = P + (size_t)(n0 + fr)*PW + colb[ch] + fc*8;
            float4 v0 = *(const float4*)ap;
            float4 v1 = *(const float4*)(ap + 4);
            float vv[8] = {v0.x,v0.y,v0.z,v0.w,v1.x,v1.y,v1.z,v1.w};
#pragma unroll
            for (int i = 0; i < 8; ++i) {
                short hb = f2bf(vv[i]);
                ah[ch][i] = hb;
                al[ch][i] = f2bf(vv[i] - bf2f(hb));
            }
        }
        f32x4 acc[4];
#pragma unroll
        for (int g = 0; g < 4; ++g)
#pragma unroll
            for (int r = 0; r < 4; ++r) acc[g][r] = 0.f;
#pragma unroll
        for (int ch = 0; ch < NCH; ++ch)
#pragma unroll
            for (int g = 0; g < 4; ++g) {
                acc[g] = __builtin_amdgcn_mfma_f32_16x16x32_bf16(ah[ch], bh[g][ch], acc[g], 0, 0, 0);
                acc[g] = __builtin_amdgcn_mfma_f32_16x16x32_bf16(ah[ch], bl[g][ch], acc[g], 0, 0, 0);
                acc[g] = __builtin_amdgcn_mfma_f32_16x16x32_bf16(al[ch], bh[g][ch], acc[g], 0, 0, 0);
            }
        // lane-local LSTM update for n = n0+cc*4+r, this lane's k
        const int nb = n0 + cc*4;
        float4 cold = *(const float4*)(cbuf + srow + nb);
        float xa0[4], xa1[4];
        if (XEP) {
#pragma unroll
            for (int r = 0; r < 4; ++r) {
                float2 cx = *(const float2*)(convX + (size_t)(nb + r)*XC + tstep*64 + b*2);
                xa0[r] = cx.x; xa1[r] = cx.y;
            }
        }
        float cn[4], hv[4];
#pragma unroll
        for (int r = 0; r < 4; ++r) {
            float pg[4];
#pragma unroll
            for (int g = 0; g < 4; ++g) {
                pg[g] = acc[g][r] + bs[g];
                if (XEP) pg[g] += xa0[r]*wx0[g] + xa1[r]*wx1[g];
            }
            float gi = 1.f/(1.f + expf(-pg[0]));
            float gf = 1.f/(1.f + expf(-pg[1]));
            float gg = tanhf(pg[2]);
            float go = 1.f/(1.f + expf(-pg[3]));
            float co = (&cold.x)[r];
            cn[r] = gf*co + gi*gg;
            hv[r] = go * tanhf(cn[r]);
        }
        *(float4*)(cbuf + srow + nb) = make_float4(cn[0], cn[1], cn[2], cn[3]);
        short hh[4], hl[4];
#pragma unroll
        for (int r = 0; r < 4; ++r) {
            hh[r] = f2bf(hv[r]);
            hl[r] = f2bf(hv[r] - bf2f(hh[r]));
        }
        *(short4*)(hThi + srow + nb) = make_short4(hh[0], hh[1], hh[2], hh[3]);
        *(short4*)(hTlo + srow + nb) = make_short4(hl[0], hl[1], hl[2], hl[3]);
    }
}

// ---------------- out = h2 @ Wp + bp -> [B,HOR,N,1] ----------------
__global__ __launch_bounds__(256) void proj_T(const short* __restrict__ h2hi,
        const short* __restrict__ h2lo, const float* __restrict__ Wp,
        const float* __restrict__ bp, float* __restrict__ out) {
    __shared__ float sW[HH*HOR];
    __shared__ float sb[HOR];
    for (int i = threadIdx.x; i < HH*HOR; i += 256) sW[i] = Wp[i];
    if (threadIdx.x < HOR) sb[threadIdx.x] = bp[threadIdx.x];
    __syncthreads();
    int idx = blockIdx.x*256 + threadIdx.x;    // b*2048 + n
    int b = idx >> 11, n = idx & (NN-1);
    float acc[HOR];
#pragma unroll
    for (int j = 0; j < HOR; ++j) acc[j] = sb[j];
    for (int k = 0; k < HH; ++k) {
        size_t row = (size_t)(b*64 + k)*NN + n;
        float h = bf2f(h2hi[row]) + bf2f(h2lo[row]);
#pragma unroll
        for (int j = 0; j < HOR; ++j) acc[j] = fmaf(h, sW[k*HOR + j], acc[j]);
    }
#pragma unroll
    for (int j = 0; j < HOR; ++j)
        out[(size_t)(b*HOR + j)*NN + n] = acc[j];
}

extern "C" void kernel_launch(void* const* d_in, const int* in_sizes, int n_in,
                              void* d_out, int out_size, void* d_ws, size_t ws_size,
                              hipStream_t stream) {
    const float* x  = (const float*)d_in[0];
    const float* E  = (const float*)d_in[1];
    const float* W1 = (const float*)d_in[2];
    const float* b1 = (const float*)d_in[3];
    const float* W2 = (const float*)d_in[4];
    const float* b2 = (const float*)d_in[5];
    const float* Wp = (const float*)d_in[6];
    const float* bp = (const float*)d_in[7];
    float* out = (float*)d_out;

    char* base = (char*)d_ws;
    short* Ahi    = (short*)base; base += (size_t)NN*NN*2;        // 8.39M
    short* Alo    = (short*)base; base += (size_t)NN*NN*2;        // 8.39M
    float* convX  = (float*)base; base += (size_t)NN*XC*4;        // 12.58M
    float* P      = (float*)base; base += (size_t)NN*PW*4;        // 33.55M
    short* hAllhi = (short*)base; base += (size_t)2*NN*NN*2;      // 16.78M
    short* hAlllo = (short*)base; base += (size_t)2*NN*NN*2;      // 16.78M
    float* cs1    = (float*)base; base += (size_t)NN*NN*4;        // 16.78M
    float* cs2    = (float*)base; base += (size_t)NN*NN*4;        // 16.78M
    short* Wt2hi  = (short*)base; base += 256*128*2;
    short* Wt2lo  = (short*)base; base += 256*128*2;
    short* Wt1hi  = (short*)base; base += 256*64*2;
    short* Wt1lo  = (short*)base; base += 256*64*2;
    // XallT aliases P (consumed by convX GEMM before P is zeroed)
    short* XThi = (short*)P;
    short* XTlo = XThi + (size_t)XC*NN;
    short* h1Thi = hAllhi + (size_t)NN*NN;   // rows 2048.. = h1T
    short* h1Tlo = hAlllo + (size_t)NN*NN;

    hipMemsetAsync(cs1, 0, (size_t)NN*NN*4, stream);
    hipMemsetAsync(cs2, 0, (size_t)NN*NN*4, stream);

    compute_A_kernel<<<NN, 256, 0, stream>>>(E, Ahi, Alo);
    wsplit_T<<<(256*128 + 255)/256, 256, 0, stream>>>(W2, 0, 128, Wt2hi, Wt2lo);
    wsplit_T<<<(256*64 + 255)/256, 256, 0, stream>>>(W1, 2, 64, Wt1hi, Wt1lo);
    scatter_xall<<<(XC*NN)/256, 256, 0, stream>>>(x, XThi, XTlo);
    // convX = A @ Xall (once, all timesteps)
    gc3_gemm<<<dim3(XC/128, NN/64), 256, 0, stream>>>(Ahi, Alo, XThi, XTlo, convX, XC);
    // XT region dead -> zero P (both halves) for first-step reads
    hipMemsetAsync(P, 0, (size_t)NN*PW*4, stream);

    // cell1(0): reads P1=0 + convX(t=0) -> h1T(0)
    cell_mfma<2, true><<<dim3(NN/128, BB), 256, 0, stream>>>(
        P, convX, W1, Wt1hi, Wt1lo, b1, cs1, h1Thi, h1Tlo, 0);
    // P1(0) = A @ h1(0)
    gc3_gemm<<<dim3(NN/128, NN/64), 256, 0, stream>>>(
        Ahi, Alo, h1Thi, h1Tlo, P + 2048, PW);

    for (int t = 0; t < TT; ++t) {
        // cell2(t): reads P1(t), P2(t-1) -> h2T(t)
        cell_mfma<4, false><<<dim3(NN/128, BB), 256, 0, stream>>>(
            P, nullptr, nullptr, Wt2hi, Wt2lo, b2, cs2, hAllhi, hAlllo, 0);
        if (t < TT-1) {
            // cell1(t+1): reads P1(t), convX(t+1) -> h1T(t+1)
            cell_mfma<2, true><<<dim3(NN/128, BB), 256, 0, stream>>>(
                P, convX, W1, Wt1hi, Wt1lo, b1, cs1, h1Thi, h1Tlo, t+1);
            // merged GEMM: [P2(t) | P1(t+1)] = A @ [h2(t) | h1(t+1)]
            gc3_gemm<<<dim3(2*NN/128, NN/64), 256, 0, stream>>>(
                Ahi, Alo, hAllhi, hAlllo, P, PW);
        }
    }
    proj_T<<<(BB*NN)/256, 256, 0, stream>>>(hAllhi, hAlllo, Wp, bp, out);
}